// Round 3
// baseline (287.057 us; speedup 1.0000x reference)
//
#include <hip/hip_runtime.h>
#include <hip/hip_bf16.h>
#include <stdint.h>

// B=16, M=4096, D=64, K=1024. fp32 in / fp32 out.
// Output: [z_q_st (N*D) | indices (N) | loss (1)], fp32.
//
// R15 post-mortem: MFMA screen correct (absmax=0) and 2.4x faster, but
// OccupancyPercent=14% ==> only ONE 66KB-LDS block resident per CU (4.5
// waves/CU) -> latency-bound; all pipes <16% busy while throughput floors
// sum to ~20us. R16: (1) LDS cut to exactly 32KB (TK=128, lds_n -> 8
// prefetched regs, loss-reduce buffer aliased onto lds_eh behind a barrier)
// -> 4-5 blocks/CU; (2) grid 1024 blocks (16 rows/wave) so 4 blocks/CU
// exist; launch_bounds(256,4) caps VGPR<=128; (3) two independent 3-MFMA
// chains per ct + full ct unroll for ILP; (4) branch-free top-2 (cndmask);
// (5) prep widened to 16 blocks. Screen math unchanged (bf16 hi/lo,
// hh+hl+lh, MARGIN=0.06 >= 2x err bound; exact fp64 rescan for near-ties).
#define D_     64
#define K_     1024
#define N_     65536
#define TK     128            // codes per LDS tile
#define TPB    256            // 4 waves
#define RPB    64             // 4 waves x 16 rows
#define NBLK   (N_ / RPB)     // 1024 blocks
#define MARGIN 0.06f          // screen err bound ~1.4e-2; need >= 2x

typedef __bf16 bf16x8 __attribute__((ext_vector_type(8)));
typedef float  f32x4  __attribute__((ext_vector_type(4)));

__device__ __forceinline__ unsigned short bf16_rne(float f) {
    union { float f; uint32_t u; } v; v.f = f;
    const uint32_t u = v.u;
    return (unsigned short)((u + 0x7fffu + ((u >> 16) & 1u)) >> 16);
}
__device__ __forceinline__ float bf16_tof(unsigned short h) {
    union { uint32_t u; float f; } v; v.u = ((uint32_t)h) << 16;
    return v.f;
}
__device__ __forceinline__ __bf16 bits_bf16(unsigned short u) {
    union { unsigned short u; __bf16 h; } v; v.u = u; return v.h;
}

// ---------------------------------------------------------------------------
// Kernel A: per-code exact fp64 norm (+fp32 copy) and bf16 hi/lo codebook
// ---------------------------------------------------------------------------
__global__ __launch_bounds__(64) void vq_prep(const float* __restrict__ embed,
                                              double* __restrict__ n64,
                                              float* __restrict__ n32,
                                              unsigned short* __restrict__ ehg,
                                              unsigned short* __restrict__ elg) {
    const int k = blockIdx.x * 64 + threadIdx.x;
    const float4* e4 = (const float4*)(embed + (size_t)k * D_);
    double acc = 0.0;
#pragma unroll
    for (int q = 0; q < 16; ++q) {
        const float4 e = e4[q];
        float c[4] = {e.x, e.y, e.z, e.w};
        ushort4 h4, l4;
        unsigned short hb[4], lb[4];
#pragma unroll
        for (int j = 0; j < 4; ++j) {
            hb[j] = bf16_rne(c[j]);
            lb[j] = bf16_rne(c[j] - bf16_tof(hb[j]));
            acc = fma((double)c[j], (double)c[j], acc);
        }
        h4.x = hb[0]; h4.y = hb[1]; h4.z = hb[2]; h4.w = hb[3];
        l4.x = lb[0]; l4.y = lb[1]; l4.z = lb[2]; l4.w = lb[3];
        *(ushort4*)(ehg + (size_t)k * D_ + q * 4) = h4;
        *(ushort4*)(elg + (size_t)k * D_ + q * 4) = l4;
    }
    n64[k] = acc;
    n32[k] = (float)acc;
}

// ---------------------------------------------------------------------------
// Kernel B: MFMA screen + fused per-row top-2 + exact fp64 rescan + epilogue
// Wave = 16 rows (1 rowtile). k-map kappa(l,s,i)=(l>>4)*16+s*8+i on BOTH
// A and B frags (dot invariant to HW k wiring; verified system in R15).
// C/D: score row-in-tile = (l>>4)*4+rg, code col = ct*16+(l&15).
// ---------------------------------------------------------------------------
__global__ __launch_bounds__(TPB, 4) void vq_main(const float* __restrict__ z_e,
                                                  const float* __restrict__ embed,
                                                  const unsigned short* __restrict__ ehg,
                                                  const unsigned short* __restrict__ elg,
                                                  const float* __restrict__ n32g,
                                                  const double* __restrict__ n64g,
                                                  float* __restrict__ out,
                                                  float* __restrict__ partials) {
    __shared__ float4 lds_eh[TK * 8];   // 16 KB swizzled bf16 hi tile
    __shared__ float4 lds_el[TK * 8];   // 16 KB swizzled bf16 lo tile
    // total LDS = 32 KB exactly; loss-reduce buffer aliases lds_eh later.

    const int tid  = threadIdx.x;
    const int lane = tid & 63;
    const int w    = tid >> 6;          // wave id 0..3
    const int lg   = lane >> 4;         // k-chunk / row-group 0..3
    const int lc   = lane & 15;         // A-row within tile / code within subtile
    const int wrow0 = blockIdx.x * RPB + w * 16;

    // ---- x row: fp32 slice (dims lg*16..+16) + bf16 hi/lo A-fragments ----
    float  xs[16];
    bf16x8 ah[2], al[2];
    {
        const int row = wrow0 + lc;
        const float4* xg = (const float4*)(z_e + (size_t)row * D_ + lg * 16);
#pragma unroll
        for (int q = 0; q < 4; ++q) {
            const float4 x = xg[q];
            xs[q * 4 + 0] = x.x; xs[q * 4 + 1] = x.y;
            xs[q * 4 + 2] = x.z; xs[q * 4 + 3] = x.w;
        }
#pragma unroll
        for (int s = 0; s < 2; ++s) {
#pragma unroll
            for (int i = 0; i < 8; ++i) {
                const float xf = xs[s * 8 + i];
                const unsigned short hb = bf16_rne(xf);
                const unsigned short lb = bf16_rne(xf - bf16_tof(hb));
                ah[s][i] = bits_bf16(hb);
                al[s][i] = bits_bf16(lb);
            }
        }
    }

    float b1[4], b2[4];
    int   i1[4];
#pragma unroll
    for (int rg = 0; rg < 4; ++rg) { b1[rg] = 3.4e38f; b2[rg] = 3.4e38f; i1[rg] = 0; }

    for (int kt = 0; kt < K_; kt += TK) {
        __syncthreads();
        float nreg[8];
        {   // stage bf16 tiles, XOR-swizzled (byte s holds logical s^(((s>>7)&7)<<4))
            const float4* sh = (const float4*)(ehg + (size_t)kt * D_);
            const float4* sl = (const float4*)(elg + (size_t)kt * D_);
#pragma unroll
            for (int it = 0; it < 4; ++it) {
                const int m  = tid + it * TPB;                 // float4 chunk id
                const int sw = (m * 16) ^ ((((m * 16) >> 7) & 7) << 4);
                lds_eh[sw >> 4] = sh[m];
                lds_el[sw >> 4] = sl[m];
            }
            // per-lane norm prefetch: lane needs n32[kt + ct*16 + lc] only
#pragma unroll
            for (int ct = 0; ct < 8; ++ct) nreg[ct] = n32g[kt + ct * 16 + lc];
        }
        __syncthreads();

#pragma unroll
        for (int ct = 0; ct < TK / 16; ++ct) {
            const int cl = ct * 16 + lc;                       // tile-local code
            const int a0 = (cl * 128 + lg * 32) ^ ((cl & 7) << 4);
            const bf16x8 bh0 = *(const bf16x8*)((const char*)lds_eh + a0);
            const bf16x8 bh1 = *(const bf16x8*)((const char*)lds_eh + (a0 ^ 16));
            const bf16x8 bl0 = *(const bf16x8*)((const char*)lds_el + a0);
            const bf16x8 bl1 = *(const bf16x8*)((const char*)lds_el + (a0 ^ 16));
            // two INDEPENDENT 3-chains (k-halves s=0 / s=1)
            f32x4 acc0 = {0.f, 0.f, 0.f, 0.f};
            f32x4 acc1 = {0.f, 0.f, 0.f, 0.f};
            acc0 = __builtin_amdgcn_mfma_f32_16x16x32_bf16(ah[0], bh0, acc0, 0, 0, 0);
            acc1 = __builtin_amdgcn_mfma_f32_16x16x32_bf16(ah[1], bh1, acc1, 0, 0, 0);
            acc0 = __builtin_amdgcn_mfma_f32_16x16x32_bf16(al[0], bh0, acc0, 0, 0, 0);
            acc1 = __builtin_amdgcn_mfma_f32_16x16x32_bf16(al[1], bh1, acc1, 0, 0, 0);
            acc0 = __builtin_amdgcn_mfma_f32_16x16x32_bf16(ah[0], bl0, acc0, 0, 0, 0);
            acc1 = __builtin_amdgcn_mfma_f32_16x16x32_bf16(ah[1], bl1, acc1, 0, 0, 0);
            const int ki = kt + cl;
#pragma unroll
            for (int rg = 0; rg < 4; ++rg) {
                const float s  = fmaf(-2.0f, acc0[rg] + acc1[rg], nreg[ct]);
                const bool  lt = s < b1[rg];
                const float m2 = fminf(s, b2[rg]);   // new b2 when !lt
                b2[rg] = lt ? b1[rg] : m2;
                b1[rg] = lt ? s      : b1[rg];
                i1[rg] = lt ? ki     : i1[rg];
            }
        }
    }

    // Merge top-2 across the 16 lanes sharing rows (lex (score,idx)).
#pragma unroll
    for (int rg = 0; rg < 4; ++rg)
#pragma unroll
        for (int off = 1; off <= 8; off <<= 1) {
            const float ob1 = __shfl_xor(b1[rg], off);
            const float ob2 = __shfl_xor(b2[rg], off);
            const int   oi1 = __shfl_xor(i1[rg], off);
            if (ob1 < b1[rg] || (ob1 == b1[rg] && oi1 < i1[rg])) {
                b2[rg] = fminf(b1[rg], ob2); b1[rg] = ob1; i1[rg] = oi1;
            } else {
                b2[rg] = fminf(ob1, b2[rg]);
            }
        }

    // Near-tie rows: wave-cooperative EXACT fp64 full-K rescan (rare).
#pragma unroll
    for (int rg = 0; rg < 4; ++rg) {
        for (int g = 0; g < 4; ++g) {              // runtime loop, wave-uniform
            const float g1 = __shfl(b1[rg], g << 4);
            const float g2 = __shfl(b2[rg], g << 4);
            if (g2 - g1 < MARGIN) {
                const int grow = wrow0 + g * 4 + rg;
                const float* xp = z_e + (size_t)grow * D_;
                double bs = 1.0e300; int bi = 1 << 30;
                for (int c0 = 0; c0 < K_; c0 += 64) {
                    const int c = c0 + lane;
                    const float* ep = embed + (size_t)c * D_;
                    double dot = 0.0;
#pragma unroll
                    for (int j = 0; j < D_; ++j)
                        dot = fma((double)xp[j], (double)ep[j], dot);
                    const double sc = fma(-2.0, dot, n64g[c]);
                    if (sc < bs) { bs = sc; bi = c; }
                }
#pragma unroll
                for (int off = 32; off > 0; off >>= 1) {   // (s,idx) lex-min
                    const double so = __shfl_xor(bs, off);
                    const int    io = __shfl_xor(bi, off);
                    if (so < bs || (so == bs && io < bi)) { bs = so; bi = io; }
                }
                if (lg == g) i1[rg] = bi;
            }
        }
    }

    // Epilogue: lane owns row lc, k-chunk lg*16..+16.
    float sq = 0.f;
    {
        const int srcl = (lc >> 2) << 4;   // a lane of the group owning row lc
        const int c0v = __shfl(i1[0], srcl);
        const int c1v = __shfl(i1[1], srcl);
        const int c2v = __shfl(i1[2], srcl);
        const int c3v = __shfl(i1[3], srcl);
        const int rsel = lc & 3;
        int bidx = (rsel == 0) ? c0v : (rsel == 1) ? c1v : (rsel == 2) ? c2v : c3v;
        bidx &= (K_ - 1);
        const int row = wrow0 + lc;
        const float4* eg = (const float4*)(embed + (size_t)bidx * D_ + lg * 16);
        float4*       og = (float4*)(out + (size_t)row * D_ + lg * 16);
#pragma unroll
        for (int q = 0; q < 4; ++q) {
            const float4 e = eg[q];
            const int   x0 = q * 4;
            const float d0 = e.x - xs[x0 + 0];
            const float d1 = e.y - xs[x0 + 1];
            const float d2 = e.z - xs[x0 + 2];
            const float d3 = e.w - xs[x0 + 3];
            sq = fmaf(d0, d0, sq); sq = fmaf(d1, d1, sq);
            sq = fmaf(d2, d2, sq); sq = fmaf(d3, d3, sq);
            float4 o;                      // x + (e - x): match reference fp32 rounding
            o.x = xs[x0 + 0] + d0;
            o.y = xs[x0 + 1] + d1;
            o.z = xs[x0 + 2] + d2;
            o.w = xs[x0 + 3] + d3;
            og[q] = o;
        }
        if (lg == 0) out[(size_t)N_ * D_ + row] = (float)bidx;
    }

    // Block loss reduction; buffer ALIASES lds_eh -> barrier before reuse.
    __syncthreads();
    float* red = (float*)lds_eh;
    red[tid] = sq;
    __syncthreads();
#pragma unroll
    for (int s = TPB / 2; s > 0; s >>= 1) {
        if (tid < s) red[tid] += red[tid + s];
        __syncthreads();
    }
    if (tid == 0) partials[blockIdx.x] = red[0];
}

// ---------------------------------------------------------------------------
// Kernel C: reduce NBLK partials -> vq_loss = 1.25 * mean(sqdiff), fp32
// ---------------------------------------------------------------------------
__global__ __launch_bounds__(256) void vq_loss_final(const float* __restrict__ partials,
                                                     float* __restrict__ out) {
    __shared__ float red[256];
    const int tid = threadIdx.x;
    float s = 0.f;
#pragma unroll
    for (int i = 0; i < NBLK / 256; ++i) s += partials[tid + i * 256];
    red[tid] = s;
    __syncthreads();
#pragma unroll
    for (int w = 128; w > 0; w >>= 1) {
        if (tid < w) red[tid] += red[tid + w];
        __syncthreads();
    }
    if (tid == 0)
        out[(size_t)N_ * D_ + N_] = 1.25f * red[0] / (float)((size_t)N_ * D_);
}

// ---------------------------------------------------------------------------
extern "C" void kernel_launch(void* const* d_in, const int* in_sizes, int n_in,
                              void* d_out, int out_size, void* d_ws, size_t ws_size,
                              hipStream_t stream) {
    const float* z_e;
    const float* embed;
    if (in_sizes[0] == N_ * D_) {
        z_e   = (const float*)d_in[0];
        embed = (const float*)d_in[1];
    } else {
        z_e   = (const float*)d_in[1];
        embed = (const float*)d_in[0];
    }
    float* out = (float*)d_out;

    double* n64           = (double*)d_ws;            // 8 KB
    float*  n32           = (float*)(n64 + K_);       // 4 KB
    float*  partials      = n32 + K_;                 // 4 KB
    unsigned short* ehg   = (unsigned short*)(partials + NBLK);  // 128 KB
    unsigned short* elg   = ehg + (size_t)K_ * D_;               // 128 KB

    vq_prep<<<K_ / 64, 64, 0, stream>>>(embed, n64, n32, ehg, elg);
    vq_main<<<NBLK, TPB, 0, stream>>>(z_e, embed, ehg, elg, n32, n64, out, partials);
    vq_loss_final<<<1, 256, 0, stream>>>(partials, out);
}

// Round 4
// 191.910 us; speedup vs baseline: 1.4958x; 1.4958x over previous
//
#include <hip/hip_runtime.h>
#include <hip/hip_bf16.h>
#include <stdint.h>

// B=16, M=4096, D=64, K=1024. fp32 in / fp32 out.
// Output: [z_q_st (N*D) | indices (N) | loss (1)], fp32.
//
// R16 post-mortem: __launch_bounds__(256,4) forced VGPR=64 -> scratch spill
// (WRITE 16.6->85MB) -> 223us. Latency-starvation diagnosis from R15 stands
// (all pipes <16% busy, floors ~15-25us).
// R17: fix residency structurally, register-neutral:
//  (1) 33KB LDS (TK=128 hi+lo+norms, loss-reduce aliased) -> 4 blocks/CU;
//  (2) 1024 blocks (16 rows/wave) so 4 blocks/CU exist;
//  (3) vq_prep stores bf16 hi/lo codebook PRE-SWIZZLED in global -> LDS tile
//      is a linear image -> staging via global_load_lds width=16 (no staging
//      VGPRs, no ds_writes); launch_bounds(256,2) = no allocator forcing.
// Screen math/top-2/fp64-rescan/epilogue identical to R16 (passed, absmax=0):
// bf16 hi/lo hh+hl+lh, MARGIN=0.06 >= 2x err bound; k-map kappa on both A,B.
#define D_     64
#define K_     1024
#define N_     65536
#define TK     128            // codes per LDS tile
#define TPB    256            // 4 waves
#define RPB    64             // 4 waves x 16 rows
#define NBLK   (N_ / RPB)     // 1024 blocks
#define MARGIN 0.06f          // screen err bound ~1.4e-2; need >= 2x

typedef __bf16 bf16x8 __attribute__((ext_vector_type(8)));
typedef float  f32x4  __attribute__((ext_vector_type(4)));

__device__ __forceinline__ unsigned short bf16_rne(float f) {
    union { float f; uint32_t u; } v; v.f = f;
    const uint32_t u = v.u;
    return (unsigned short)((u + 0x7fffu + ((u >> 16) & 1u)) >> 16);
}
__device__ __forceinline__ float bf16_tof(unsigned short h) {
    union { uint32_t u; float f; } v; v.u = ((uint32_t)h) << 16;
    return v.f;
}

// async global->LDS: per-lane global src, wave-uniform LDS base + lane*size
__device__ __forceinline__ void gld16(void* l, const void* g) {
    __builtin_amdgcn_global_load_lds(
        (const __attribute__((address_space(1))) uint32_t*)g,
        (__attribute__((address_space(3))) uint32_t*)l, 16, 0, 0);
}
__device__ __forceinline__ void gld4(void* l, const void* g) {
    __builtin_amdgcn_global_load_lds(
        (const __attribute__((address_space(1))) uint32_t*)g,
        (__attribute__((address_space(3))) uint32_t*)l, 4, 0, 0);
}

// ---------------------------------------------------------------------------
// Kernel A: exact fp64 norms (+fp32 copy) and PRE-SWIZZLED bf16 hi/lo
// codebook. Tile t (=k>>7) is a 16KB block; chunk q of code cl stored at
// byte ((cl*128 + q*16) ^ ((cl&7)<<4)) -- the exact LDS image vq_main wants.
// ---------------------------------------------------------------------------
__global__ __launch_bounds__(64) void vq_prep(const float* __restrict__ embed,
                                              double* __restrict__ n64,
                                              float* __restrict__ n32,
                                              uint32_t* __restrict__ ehg,
                                              uint32_t* __restrict__ elg) {
    const int k = blockIdx.x * 64 + threadIdx.x;
    const float4* e4 = (const float4*)(embed + (size_t)k * D_);
    double acc = 0.0;
    uint32_t hw[32], lw[32];
#pragma unroll
    for (int q = 0; q < 16; ++q) {
        const float4 e = e4[q];
        float c[4] = {e.x, e.y, e.z, e.w};
        unsigned short hb[4], lb[4];
#pragma unroll
        for (int j = 0; j < 4; ++j) {
            hb[j] = bf16_rne(c[j]);
            lb[j] = bf16_rne(c[j] - bf16_tof(hb[j]));
            acc = fma((double)c[j], (double)c[j], acc);
        }
        hw[q * 2]     = (uint32_t)hb[0] | ((uint32_t)hb[1] << 16);
        hw[q * 2 + 1] = (uint32_t)hb[2] | ((uint32_t)hb[3] << 16);
        lw[q * 2]     = (uint32_t)lb[0] | ((uint32_t)lb[1] << 16);
        lw[q * 2 + 1] = (uint32_t)lb[2] | ((uint32_t)lb[3] << 16);
    }
    const int t = k >> 7, cl = k & 127;
    char* hb8 = (char*)ehg + (size_t)t * 16384;
    char* lb8 = (char*)elg + (size_t)t * 16384;
#pragma unroll
    for (int q = 0; q < 8; ++q) {
        const int S = (cl * 128 + q * 16) ^ ((cl & 7) << 4);
        int4 hv; hv.x = hw[q*4]; hv.y = hw[q*4+1]; hv.z = hw[q*4+2]; hv.w = hw[q*4+3];
        int4 lv; lv.x = lw[q*4]; lv.y = lw[q*4+1]; lv.z = lw[q*4+2]; lv.w = lw[q*4+3];
        *(int4*)(hb8 + S) = hv;
        *(int4*)(lb8 + S) = lv;
    }
    n64[k] = acc;
    n32[k] = (float)acc;
}

// ---------------------------------------------------------------------------
// Kernel B: MFMA screen + fused per-row top-2 + exact fp64 rescan + epilogue
// Wave = 16 rows. k-map kappa(l,s,i)=(l>>4)*16+s*8+i on BOTH A and B frags.
// C/D: score for x-row (l>>4)*4+rg, code ct*16+(l&15)  (m89/m91-verified).
// ---------------------------------------------------------------------------
__global__ __launch_bounds__(TPB, 2) void vq_main(const float* __restrict__ z_e,
                                                  const float* __restrict__ embed,
                                                  const uint32_t* __restrict__ ehg,
                                                  const uint32_t* __restrict__ elg,
                                                  const float* __restrict__ n32g,
                                                  const double* __restrict__ n64g,
                                                  float* __restrict__ out,
                                                  float* __restrict__ partials) {
    __shared__ float4 lds_eh[TK * 8];   // 16 KB swizzled bf16 hi tile
    __shared__ float4 lds_el[TK * 8];   // 16 KB swizzled bf16 lo tile
    __shared__ float  lds_n[TK];        // 512 B; total 33280 B -> 4 blocks/CU

    const int tid  = threadIdx.x;
    const int lane = tid & 63;
    const int w    = tid >> 6;          // wave id 0..3
    const int lg   = lane >> 4;         // k-chunk / row-group 0..3
    const int lc   = lane & 15;         // A-row within tile / code within subtile
    const int wrow0 = blockIdx.x * RPB + w * 16;

    // ---- x row: fp32 slice (dims lg*16..+16) + bf16 hi/lo A-fragments ----
    float  xs[16];
    bf16x8 ah[2], al[2];
    {
        const int row = wrow0 + lc;
        const float4* xg = (const float4*)(z_e + (size_t)row * D_ + lg * 16);
#pragma unroll
        for (int q = 0; q < 4; ++q) {
            const float4 x = xg[q];
            xs[q * 4 + 0] = x.x; xs[q * 4 + 1] = x.y;
            xs[q * 4 + 2] = x.z; xs[q * 4 + 3] = x.w;
        }
#pragma unroll
        for (int s = 0; s < 2; ++s) {
#pragma unroll
            for (int i = 0; i < 8; ++i) {
                const float xf = xs[s * 8 + i];
                const unsigned short hb = bf16_rne(xf);
                const unsigned short lb = bf16_rne(xf - bf16_tof(hb));
                union { unsigned short u; __bf16 h; } uh, ul;
                uh.u = hb; ul.u = lb;
                ah[s][i] = uh.h;
                al[s][i] = ul.h;
            }
        }
    }

    float b1[4], b2[4];
    int   i1[4];
#pragma unroll
    for (int rg = 0; rg < 4; ++rg) { b1[rg] = 3.4e38f; b2[rg] = 3.4e38f; i1[rg] = 0; }

    for (int kt = 0; kt < K_; kt += TK) {
        __syncthreads();               // previous tile fully consumed
        {   // stage: linear async copy of the pre-swizzled 16KB tiles.
            // wave w covers bytes [w*4KB, (w+1)*4KB) in 4 chunks of 1KB.
            const char* sh = (const char*)ehg + (size_t)kt * 128;
            const char* sl = (const char*)elg + (size_t)kt * 128;
            char* dh = (char*)lds_eh;
            char* dl = (char*)lds_el;
            const int wb = w * 4096;
#pragma unroll
            for (int i = 0; i < 4; ++i) {
                const int off = wb + i * 1024;
                gld16(dh + off, sh + off + lane * 16);
                gld16(dl + off, sl + off + lane * 16);
            }
            if (w == 0) {
                gld4((char*)lds_n,       (const char*)(n32g + kt)      + lane * 4);
                gld4((char*)lds_n + 256, (const char*)(n32g + kt + 64) + lane * 4);
            }
        }
        __syncthreads();               // compiler drains vmcnt before barrier

#pragma unroll
        for (int ct = 0; ct < TK / 16; ++ct) {
            const int cl = ct * 16 + lc;                       // tile-local code
            const int a0 = (cl * 128 + lg * 32) ^ ((cl & 7) << 4);
            const bf16x8 bh0 = *(const bf16x8*)((const char*)lds_eh + a0);
            const bf16x8 bh1 = *(const bf16x8*)((const char*)lds_eh + (a0 ^ 16));
            const bf16x8 bl0 = *(const bf16x8*)((const char*)lds_el + a0);
            const bf16x8 bl1 = *(const bf16x8*)((const char*)lds_el + (a0 ^ 16));
            // two INDEPENDENT 3-chains (k-halves s=0 / s=1)
            f32x4 acc0 = {0.f, 0.f, 0.f, 0.f};
            f32x4 acc1 = {0.f, 0.f, 0.f, 0.f};
            acc0 = __builtin_amdgcn_mfma_f32_16x16x32_bf16(ah[0], bh0, acc0, 0, 0, 0);
            acc1 = __builtin_amdgcn_mfma_f32_16x16x32_bf16(ah[1], bh1, acc1, 0, 0, 0);
            acc0 = __builtin_amdgcn_mfma_f32_16x16x32_bf16(al[0], bh0, acc0, 0, 0, 0);
            acc1 = __builtin_amdgcn_mfma_f32_16x16x32_bf16(al[1], bh1, acc1, 0, 0, 0);
            acc0 = __builtin_amdgcn_mfma_f32_16x16x32_bf16(ah[0], bl0, acc0, 0, 0, 0);
            acc1 = __builtin_amdgcn_mfma_f32_16x16x32_bf16(ah[1], bl1, acc1, 0, 0, 0);
            const int   ki = kt + cl;
            const float nv = lds_n[cl];
#pragma unroll
            for (int rg = 0; rg < 4; ++rg) {
                const float s  = fmaf(-2.0f, acc0[rg] + acc1[rg], nv);
                const bool  lt = s < b1[rg];
                const float m2 = fminf(s, b2[rg]);   // new b2 when !lt
                b2[rg] = lt ? b1[rg] : m2;
                b1[rg] = lt ? s      : b1[rg];
                i1[rg] = lt ? ki     : i1[rg];
            }
        }
    }

    // Merge top-2 across the 16 lanes sharing rows (lex (score,idx)).
#pragma unroll
    for (int rg = 0; rg < 4; ++rg)
#pragma unroll
        for (int off = 1; off <= 8; off <<= 1) {
            const float ob1 = __shfl_xor(b1[rg], off);
            const float ob2 = __shfl_xor(b2[rg], off);
            const int   oi1 = __shfl_xor(i1[rg], off);
            if (ob1 < b1[rg] || (ob1 == b1[rg] && oi1 < i1[rg])) {
                b2[rg] = fminf(b1[rg], ob2); b1[rg] = ob1; i1[rg] = oi1;
            } else {
                b2[rg] = fminf(ob1, b2[rg]);
            }
        }

    // Near-tie rows: wave-cooperative EXACT fp64 full-K rescan (rare).
#pragma unroll
    for (int rg = 0; rg < 4; ++rg) {
        for (int g = 0; g < 4; ++g) {              // runtime loop, wave-uniform
            const float g1 = __shfl(b1[rg], g << 4);
            const float g2 = __shfl(b2[rg], g << 4);
            if (g2 - g1 < MARGIN) {
                const int grow = wrow0 + g * 4 + rg;
                const float* xp = z_e + (size_t)grow * D_;
                double bs = 1.0e300; int bi = 1 << 30;
                for (int c0 = 0; c0 < K_; c0 += 64) {
                    const int c = c0 + lane;
                    const float* ep = embed + (size_t)c * D_;
                    double dot = 0.0;
#pragma unroll
                    for (int j = 0; j < D_; ++j)
                        dot = fma((double)xp[j], (double)ep[j], dot);
                    const double sc = fma(-2.0, dot, n64g[c]);
                    if (sc < bs) { bs = sc; bi = c; }
                }
#pragma unroll
                for (int off = 32; off > 0; off >>= 1) {   // (s,idx) lex-min
                    const double so = __shfl_xor(bs, off);
                    const int    io = __shfl_xor(bi, off);
                    if (so < bs || (so == bs && io < bi)) { bs = so; bi = io; }
                }
                if (lg == g) i1[rg] = bi;
            }
        }
    }

    // Epilogue: lane owns row lc, k-chunk lg*16..+16.
    float sq = 0.f;
    {
        const int srcl = (lc >> 2) << 4;   // a lane of the group owning row lc
        const int c0v = __shfl(i1[0], srcl);
        const int c1v = __shfl(i1[1], srcl);
        const int c2v = __shfl(i1[2], srcl);
        const int c3v = __shfl(i1[3], srcl);
        const int rsel = lc & 3;
        int bidx = (rsel == 0) ? c0v : (rsel == 1) ? c1v : (rsel == 2) ? c2v : c3v;
        bidx &= (K_ - 1);
        const int row = wrow0 + lc;
        const float4* eg = (const float4*)(embed + (size_t)bidx * D_ + lg * 16);
        float4*       og = (float4*)(out + (size_t)row * D_ + lg * 16);
#pragma unroll
        for (int q = 0; q < 4; ++q) {
            const float4 e = eg[q];
            const int   x0 = q * 4;
            const float d0 = e.x - xs[x0 + 0];
            const float d1 = e.y - xs[x0 + 1];
            const float d2 = e.z - xs[x0 + 2];
            const float d3 = e.w - xs[x0 + 3];
            sq = fmaf(d0, d0, sq); sq = fmaf(d1, d1, sq);
            sq = fmaf(d2, d2, sq); sq = fmaf(d3, d3, sq);
            float4 o;                      // x + (e - x): match reference fp32 rounding
            o.x = xs[x0 + 0] + d0;
            o.y = xs[x0 + 1] + d1;
            o.z = xs[x0 + 2] + d2;
            o.w = xs[x0 + 3] + d3;
            og[q] = o;
        }
        if (lg == 0) out[(size_t)N_ * D_ + row] = (float)bidx;
    }

    // Block loss reduction; buffer ALIASES lds_eh -> barrier before reuse.
    __syncthreads();
    float* red = (float*)lds_eh;
    red[tid] = sq;
    __syncthreads();
#pragma unroll
    for (int s = TPB / 2; s > 0; s >>= 1) {
        if (tid < s) red[tid] += red[tid + s];
        __syncthreads();
    }
    if (tid == 0) partials[blockIdx.x] = red[0];
}

// ---------------------------------------------------------------------------
// Kernel C: reduce NBLK partials -> vq_loss = 1.25 * mean(sqdiff), fp32
// ---------------------------------------------------------------------------
__global__ __launch_bounds__(256) void vq_loss_final(const float* __restrict__ partials,
                                                     float* __restrict__ out) {
    __shared__ float red[256];
    const int tid = threadIdx.x;
    float s = 0.f;
#pragma unroll
    for (int i = 0; i < NBLK / 256; ++i) s += partials[tid + i * 256];
    red[tid] = s;
    __syncthreads();
#pragma unroll
    for (int w = 128; w > 0; w >>= 1) {
        if (tid < w) red[tid] += red[tid + w];
        __syncthreads();
    }
    if (tid == 0)
        out[(size_t)N_ * D_ + N_] = 1.25f * red[0] / (float)((size_t)N_ * D_);
}

// ---------------------------------------------------------------------------
extern "C" void kernel_launch(void* const* d_in, const int* in_sizes, int n_in,
                              void* d_out, int out_size, void* d_ws, size_t ws_size,
                              hipStream_t stream) {
    const float* z_e;
    const float* embed;
    if (in_sizes[0] == N_ * D_) {
        z_e   = (const float*)d_in[0];
        embed = (const float*)d_in[1];
    } else {
        z_e   = (const float*)d_in[1];
        embed = (const float*)d_in[0];
    }
    float* out = (float*)d_out;

    double* n64    = (double*)d_ws;                  // 8 KB
    float*  n32    = (float*)(n64 + K_);             // 4 KB
    float*  partials = n32 + K_;                     // 4 KB
    uint32_t* ehg  = (uint32_t*)(partials + NBLK);   // 128 KB (pre-swizzled)
    uint32_t* elg  = ehg + (size_t)K_ * D_ / 2;      // 128 KB (pre-swizzled)

    vq_prep<<<K_ / 64, 64, 0, stream>>>(embed, n64, n32, ehg, elg);
    vq_main<<<NBLK, TPB, 0, stream>>>(z_e, embed, ehg, elg, n32, n64, out, partials);
    vq_loss_final<<<1, 256, 0, stream>>>(partials, out);
}